// Round 9
// baseline (291.036 us; speedup 1.0000x reference)
//
#include <hip/hip_runtime.h>
#include <cstdint>

// GCN forward on MI355X (gfx950). f32 in/out; bf16 MFMA with fp32 accum.
// Round 18: fp8-e4m3 S1 + interleaved gathers.
//  - spmm1 was fabric-BW-bound: 800k x 512B row-gathers, per-XCD L2 replication
//    -> 175MB fetch @ ~2.9TB/s = 60us. S1's only consumer is this gather, so
//    S1 is now fp8 e4m3 (12.8MB): gather bytes halve. Decode is a 3-op bit
//    trick (finite for ALL bit patterns -> zero-pad safe); encode is magic-add
//    RNE in gemm1's epilogue. H stays bf16 (built in LDS), S2 stays bf16.
//  - both gather kernels: 4-node interleaved, 8-deep batches (32 loads in
//    flight/wave); tails zero-selected (src 0, w=0).
// Chain: memset(fill) -> [bucketA || Wtranspose] -> [gemm1(fp8 out) || csr_sort]
//   -> spmm1+bias+relu+gemm2 -> spmm2+bias+log_softmax.

typedef unsigned char u8;
typedef unsigned short u16;
typedef unsigned int u32;
typedef unsigned long long u64;
typedef __attribute__((ext_vector_type(8))) short bf16x8;
typedef __attribute__((ext_vector_type(4))) float f32x4;

#define N_NODES 50000
#define N_EDGES 800000
#define NFEAT 512
#define NHID 256
#define NCLASS 64
#define CSTRIDE 64        // fixed CSR slots per node (max deg << 64)

#define NBUCK 196         // coarse buckets: dst>>8 (50000/256)
#define BCAP 5120         // bucket region capacity (mean 4096 + 16 sigma)
#define SCB 391           // bucket-scatter blocks: ceil(800000/2048)
#define GB1 782           // gemm1 blocks: ceil(50000/64)
#define PW1B 512          // W1T transpose blocks
#define PW2B 64           // W2T transpose blocks
#define FNB 3125          // fused spmm1+gemm2 blocks: 50000/16

__device__ __forceinline__ float bf2f(u16 h) {
    union { u32 u; float f; } c; c.u = ((u32)h) << 16; return c.f;
}
__device__ __forceinline__ u16 f2bf(float f) {
    union { float f; u32 u; } c; c.f = f;
    u32 u = c.u;
    return (u16)((u + 0x7fffu + ((u >> 16) & 1u)) >> 16);   // RNE
}
__device__ __forceinline__ u32 pk2(float a, float b) {
    return (u32)f2bf(a) | ((u32)f2bf(b) << 16);
}
__device__ __forceinline__ float asf(u32 u) {
    union { u32 u; float f; } c; c.u = u; return c.f;
}
// f32 -> e4m3fn byte, RNE via magic-add on the 2^-120-scaled bit pattern.
__device__ __forceinline__ u32 f2f8(float f) {
    f = fmaxf(fminf(f, 448.f), -448.f);
    union { float f; u32 u; } c; c.f = f * 0x1p-120f;
    u32 u = c.u;
    u32 r = u + 0x7FFFFu + ((u >> 20) & 1u);
    return ((u >> 24) & 0x80u) | ((r >> 20) & 0x7Fu);
}

// async global->LDS, 16B per lane; LDS dest = wave-uniform base + lane*16.
__device__ __forceinline__ void async16(const void* g, void* l) {
    __builtin_amdgcn_global_load_lds(
        (const __attribute__((address_space(1))) void*)(uintptr_t)g,
        (__attribute__((address_space(3))) void*)(uintptr_t)l, 16, 0, 0);
}

// ---------------- dispatch 1: bucketA scatter || W1/W2 transpose+cvt ----------------

__global__ __launch_bounds__(256) void prep_scatter_kernel(
    const float* __restrict__ W1, u16* __restrict__ W1T,
    const float* __restrict__ W2, u16* __restrict__ W2T,
    const int* __restrict__ esrc, const int* __restrict__ edst,
    const float* __restrict__ ew, int* __restrict__ fill, u64* __restrict__ region) {
    __shared__ int cnt[NBUCK];
    __shared__ int base[NBUCK];
    int b = blockIdx.x, tid = threadIdx.x;
    if (b < SCB) {
        if (tid < NBUCK) cnt[tid] = 0;
        __syncthreads();
        int e0 = b * 2048 + tid * 8;
        int d[8], s[8], rk[8];
        float w[8];
        bool act = (e0 < N_EDGES);      // 800000 % 8 == 0: full chunks only
        if (act) {
            int4 d0 = *(const int4*)(edst + e0),  d1 = *(const int4*)(edst + e0 + 4);
            int4 s0 = *(const int4*)(esrc + e0),  s1 = *(const int4*)(esrc + e0 + 4);
            float4 w0 = *(const float4*)(ew + e0), w1 = *(const float4*)(ew + e0 + 4);
            d[0]=d0.x; d[1]=d0.y; d[2]=d0.z; d[3]=d0.w;
            d[4]=d1.x; d[5]=d1.y; d[6]=d1.z; d[7]=d1.w;
            s[0]=s0.x; s[1]=s0.y; s[2]=s0.z; s[3]=s0.w;
            s[4]=s1.x; s[5]=s1.y; s[6]=s1.z; s[7]=s1.w;
            w[0]=w0.x; w[1]=w0.y; w[2]=w0.z; w[3]=w0.w;
            w[4]=w1.x; w[5]=w1.y; w[6]=w1.z; w[7]=w1.w;
            #pragma unroll
            for (int i = 0; i < 8; ++i)
                rk[i] = atomicAdd(&cnt[d[i] >> 8], 1);   // LDS atomic: block-local rank
        }
        __syncthreads();
        if (tid < NBUCK) base[tid] = atomicAdd(&fill[tid], cnt[tid]);
        __syncthreads();
        if (act) {
            #pragma unroll
            for (int i = 0; i < 8; ++i) {
                int g = d[i] >> 8;
                int pos = base[g] + rk[i];
                if (pos < BCAP) {
                    u64 en = ((u64)(d[i] & 255) << 32) |
                             (u64)((u32)s[i] | ((u32)f2bf(w[i]) << 16));
                    region[(size_t)g * BCAP + pos] = en;
                }
            }
        }
    } else if (b < SCB + PW1B) {
        int idx = (b - SCB) * 256 + tid;           // W1T[256][512]
        int n = idx >> 9, k = idx & 511;
        W1T[idx] = f2bf(W1[(size_t)k * NHID + n]);
    } else {
        int idx = (b - SCB - PW1B) * 256 + tid;    // W2T[64][256]
        int n = idx >> 8, k = idx & 255;
        W2T[idx] = f2bf(W2[(size_t)k * NCLASS + n]);
    }
}

// ---------------- gemm1 body: S8[M,256] fp8 = cvt(x[M,512]bf16 @ W1T^T) ----------------
// R15 structure: A reg-staged f32->bf16 (swizzled ds_write), B async16-staged
// (pre-swizzled global source). 4 waves 1x4, BK=64. Epilogue packs fp8.

__device__ __forceinline__ void gemm1_body(const float* __restrict__ x,
                                           const u16* __restrict__ BT,
                                           u8* __restrict__ C, int M,
                                           int bid, u16* lds) {
    u16* As = lds;             // [64][64] swizzled
    u16* Bs = lds + 64 * 64;   // [256][64] swizzled (B^T: row n, k-contig)

    const int tid  = threadIdx.x;
    const int wv   = tid >> 6, lane = tid & 63;
    const int lm   = lane & 15, quad = lane >> 4;
    const int wcol = wv;                 // WROWS=1, WCOLS=4
    const int m0   = bid * 64;
    const int co0 = ((0 * 4 + quad) ^ (lm & 7)) * 8;
    const int co1 = ((1 * 4 + quad) ^ (lm & 7)) * 8;

    f32x4 acc[4][4];
    #pragma unroll
    for (int r = 0; r < 4; ++r)
        #pragma unroll
        for (int c = 0; c < 4; ++c) acc[r][c] = (f32x4){0.f, 0.f, 0.f, 0.f};

    for (int k0 = 0; k0 < NFEAT; k0 += 64) {
        // issue A f32 loads first (reg), then B DMA, then pack+write.
        int row = tid >> 2, ko = (tid & 3) * 16;
        int gr = m0 + row; if (gr > M - 1) gr = M - 1;
        const float4* gp = (const float4*)(x + (size_t)gr * NFEAT + k0 + ko);
        float4 f0 = gp[0], f1 = gp[1], f2 = gp[2], f3 = gp[3];
        #pragma unroll
        for (int i = 0; i < 8; ++i) {
            int c = i * 256 + tid;
            int n = c >> 3, kb = c & 7;
            async16(BT + (size_t)n * NFEAT + k0 + ((kb ^ (n & 7)) * 8), Bs + c * 8);
        }
        u32 p[8] = {pk2(f0.x, f0.y), pk2(f0.z, f0.w), pk2(f1.x, f1.y), pk2(f1.z, f1.w),
                    pk2(f2.x, f2.y), pk2(f2.z, f2.w), pk2(f3.x, f3.y), pk2(f3.z, f3.w)};
        int ch0 = (2 * (tid & 3))     ^ (row & 7);
        int ch1 = (2 * (tid & 3) + 1) ^ (row & 7);
        *(int4*)(As + row * 64 + ch0 * 8) = *(int4*)&p[0];
        *(int4*)(As + row * 64 + ch1 * 8) = *(int4*)&p[4];
        __syncthreads();   // drains async vmcnt + lgkm (ds_write)

        #pragma unroll
        for (int kk = 0; kk < 2; ++kk) {
            const int co = kk ? co1 : co0;
            bf16x8 af[4], bfv[4];
            #pragma unroll
            for (int rt = 0; rt < 4; ++rt)
                af[rt] = *(const bf16x8*)(As + (rt * 16 + lm) * 64 + co);
            #pragma unroll
            for (int ct = 0; ct < 4; ++ct) {
                int n = wcol * 64 + ct * 16 + lm;
                bfv[ct] = *(const bf16x8*)(Bs + n * 64 + co);
            }
            #pragma unroll
            for (int rt = 0; rt < 4; ++rt)
                #pragma unroll
                for (int ct = 0; ct < 4; ++ct)
                    acc[rt][ct] = __builtin_amdgcn_mfma_f32_16x16x32_bf16(
                        af[rt], bfv[ct], acc[rt][ct], 0, 0, 0);
        }
        __syncthreads();
    }

    // epilogue: fp8 pack through LDS (u8 [64][256] = 16KB), linear store
    u8* lds8 = (u8*)lds;
    #pragma unroll
    for (int rt = 0; rt < 4; ++rt)
        #pragma unroll
        for (int ct = 0; ct < 4; ++ct) {
            int col = wcol * 64 + ct * 16 + lm;
            #pragma unroll
            for (int r = 0; r < 4; ++r) {
                int row = rt * 16 + quad * 4 + r;   // C/D: row = quad*4 + reg
                lds8[row * 256 + col] = (u8)f2f8(acc[rt][ct][r]);
            }
        }
    __syncthreads();
    #pragma unroll
    for (int i = 0; i < 4; ++i) {
        int c = i * 256 + tid;                      // 1024 chunks of 16B
        int row = c >> 4, ch = c & 15;
        if (m0 + row < M)
            *(int4*)(C + (size_t)(m0 + row) * 256 + ch * 16) = *(const int4*)(lds8 + c * 16);
    }
}

// ---------------- dispatch 2: gemm1 || csr_sort ----------------

__global__ __launch_bounds__(256) void gemm1_sort_kernel(
    const float* __restrict__ x, const u16* __restrict__ W1T, u8* __restrict__ S8,
    const u64* __restrict__ region, const int* __restrict__ fill,
    u32* __restrict__ csr, int* __restrict__ deg) {
    __shared__ __align__(16) u16 lds[(64 + 256) * 64];   // 40KB
    int b = blockIdx.x, tid = threadIdx.x;
    if (b < NBUCK) {
        int* cnt2 = (int*)lds;          // [256]
        cnt2[tid] = 0;
        __syncthreads();
        int Eb = fill[b]; if (Eb > BCAP) Eb = BCAP;
        for (int i = tid; i < Eb; i += 256) {
            u64 en = region[(size_t)b * BCAP + i];
            int dlo = (int)(en >> 32) & 255;
            int r = atomicAdd(&cnt2[dlo], 1);
            if (r < CSTRIDE)
                csr[(size_t)(b * 256 + dlo) * CSTRIDE + r] = (u32)en;
        }
        __syncthreads();
        int node = b * 256 + tid;
        if (node < N_NODES) {
            int dg = cnt2[tid]; if (dg > CSTRIDE) dg = CSTRIDE;
            deg[node] = dg;
        }
    } else {
        gemm1_body(x, W1T, S8, N_NODES, b - NBUCK, lds);
    }
}

// ---------------- fused SpMM1(fp8 gather) + bias + ReLU + gemm2 ----------------
// Block = 4 waves = 16 nodes. Phase 1: each wave processes its 4 nodes
// INTERLEAVED (8-deep batches x 4 nodes = 32 gathers in flight); fp8 decode is
// a bit-trick (finite for all patterns); tails zero-selected. Phase 2:
// 16x64x256 MFMA vs W2T direct from L2; S2 via LDS repack.

__global__ __launch_bounds__(256) void spmm1_gemm2_kernel(
    const u8* __restrict__ S8, const int* __restrict__ deg,
    const u32* __restrict__ csr, const float* __restrict__ bias1,
    const u16* __restrict__ W2T, u16* __restrict__ S2) {
    __shared__ __align__(16) u16 Hs[16 * 256];   // [16][256] swizzled; reused for repack

    const int tid  = threadIdx.x;
    const int wv   = tid >> 6, lane = tid & 63;
    const int lm   = lane & 15, quad = lane >> 4;
    const int b    = blockIdx.x;

    float4 bv = *(const float4*)(bias1 + lane * 4);

    int begs[4], degs[4];
    int maxd = 0;
    #pragma unroll
    for (int n = 0; n < 4; ++n) {
        int node = __builtin_amdgcn_readfirstlane(b * 16 + wv * 4 + n);
        begs[n] = node * CSTRIDE;
        degs[n] = deg[node];
        maxd = max(maxd, degs[n]);
    }

    float a[4][4];
    #pragma unroll
    for (int n = 0; n < 4; ++n)
        #pragma unroll
        for (int k = 0; k < 4; ++k) a[n][k] = 0.f;

    for (int kb = 0; kb < maxd; kb += 8) {
        u32 e[4][8];
        #pragma unroll
        for (int n = 0; n < 4; ++n)
            #pragma unroll
            for (int i = 0; i < 8; ++i) {
                u32 t = csr[begs[n] + kb + i];            // uniform -> s_load
                e[n][i] = (kb + i < degs[n]) ? t : 0u;    // pad: src 0, w 0
            }
        u32 q[4][8];
        #pragma unroll
        for (int n = 0; n < 4; ++n)
            #pragma unroll
            for (int i = 0; i < 8; ++i)
                q[n][i] = *(const u32*)(S8 + (size_t)(e[n][i] & 0xFFFFu) * NHID + lane * 4);
        #pragma unroll
        for (int n = 0; n < 4; ++n)
            #pragma unroll
            for (int i = 0; i < 8; ++i) {
                float w = bf2f((u16)(e[n][i] >> 16)) * 0x1p120f;  // fold fp8 scale
                u32 qq = q[n][i];
                a[n][0] += w * asf(((qq & 0x80u) << 24) | ((qq & 0x7Fu) << 20));
                a[n][1] += w * asf(((qq & 0x8000u) << 16) | ((qq & 0x7F00u) << 12));
                a[n][2] += w * asf(((qq & 0x800000u) << 8) | ((qq & 0x7F0000u) << 4));
                a[n][3] += w * asf((qq & 0x80000000u) | ((qq & 0x7F000000u) >> 4));
            }
    }

    #pragma unroll
    for (int n = 0; n < 4; ++n) {
        int lrow = wv * 4 + n;
        float a0 = fmaxf(a[n][0] + bv.x, 0.f);
        float a1 = fmaxf(a[n][1] + bv.y, 0.f);
        float a2 = fmaxf(a[n][2] + bv.z, 0.f);
        float a3 = fmaxf(a[n][3] + bv.w, 0.f);
        int ch = (lane >> 1) ^ (lrow & 7);
        u32* dp = (u32*)(Hs + lrow * 256 + ch * 8 + (lane & 1) * 4);
        dp[0] = pk2(a0, a1);
        dp[1] = pk2(a2, a3);
    }
    __syncthreads();

    // ---- phase 2: S2[16][64] = H[16][256] @ W2T^T, B direct from L2 ----
    f32x4 acc = (f32x4){0.f, 0.f, 0.f, 0.f};
    #pragma unroll
    for (int k0 = 0; k0 < NHID; k0 += 64) {
        #pragma unroll
        for (int kk = 0; kk < 2; ++kk) {
            int ca = ((k0 >> 3) + kk * 4 + quad) ^ (lm & 7);
            bf16x8 af = *(const bf16x8*)(Hs + lm * 256 + ca * 8);
            int n = wv * 16 + lm;
            bf16x8 bf = *(const bf16x8*)(W2T + (size_t)n * NHID + k0 + kk * 32 + quad * 8);
            acc = __builtin_amdgcn_mfma_f32_16x16x32_bf16(af, bf, acc, 0, 0, 0);
        }
    }
    __syncthreads();

    #pragma unroll
    for (int r = 0; r < 4; ++r) {
        int row = quad * 4 + r;                  // C/D: row = quad*4 + reg
        Hs[row * 64 + wv * 16 + lm] = f2bf(acc[r]);
    }
    __syncthreads();
    *(ushort4*)(S2 + (size_t)b * 1024 + tid * 4) = *(const ushort4*)(Hs + tid * 4);
}

// ---------------- SpMM2 + bias + log_softmax (4 nodes/wave interleaved) ----------------

__global__ __launch_bounds__(256) void spmm_bias_lsm_kernel(
    const u16* __restrict__ S, const int* __restrict__ deg,
    const u32* __restrict__ csr, const float* __restrict__ bias,
    float* __restrict__ out) {
    const int tid = threadIdx.x;
    const int wv = tid >> 6, lane = tid & 63;
    const int b = blockIdx.x;

    int begs[4], degs[4];
    int maxd = 0;
    #pragma unroll
    for (int n = 0; n < 4; ++n) {
        int node = __builtin_amdgcn_readfirstlane(b * 16 + wv * 4 + n);
        begs[n] = node * CSTRIDE;
        degs[n] = deg[node];
        maxd = max(maxd, degs[n]);
    }

    float acc[4] = {0.f, 0.f, 0.f, 0.f};
    for (int kb = 0; kb < maxd; kb += 8) {
        u32 e[4][8];
        #pragma unroll
        for (int n = 0; n < 4; ++n)
            #pragma unroll
            for (int i = 0; i < 8; ++i) {
                u32 t = csr[begs[n] + kb + i];            // uniform -> s_load
                e[n][i] = (kb + i < degs[n]) ? t : 0u;    // pad: src 0, w 0
            }
        u16 v[4][8];
        #pragma unroll
        for (int n = 0; n < 4; ++n)
            #pragma unroll
            for (int i = 0; i < 8; ++i)
                v[n][i] = S[(size_t)(e[n][i] & 0xFFFFu) * NCLASS + lane];
        #pragma unroll
        for (int n = 0; n < 4; ++n)
            #pragma unroll
            for (int i = 0; i < 8; ++i)
                acc[n] += bf2f((u16)(e[n][i] >> 16)) * bf2f(v[n][i]);
    }

    float bl = bias[lane];
    #pragma unroll
    for (int n = 0; n < 4; ++n) {
        int node = b * 16 + wv * 4 + n;
        float x = acc[n] + bl;
        float m = x;
        #pragma unroll
        for (int off = 32; off > 0; off >>= 1) m = fmaxf(m, __shfl_xor(m, off));
        float e = expf(x - m);
        float ssum = e;
        #pragma unroll
        for (int off = 32; off > 0; off >>= 1) ssum += __shfl_xor(ssum, off);
        out[(size_t)node * NCLASS + lane] = x - m - logf(ssum);
    }
}

// ---------------- launch ----------------

extern "C" void kernel_launch(void* const* d_in, const int* in_sizes, int n_in,
                              void* d_out, int out_size, void* d_ws, size_t ws_size,
                              hipStream_t stream) {
    const float* x  = (const float*)d_in[0];   // [50000,512]
    const float* W1 = (const float*)d_in[1];   // [512,256]
    const float* b1 = (const float*)d_in[2];   // [256]
    const float* W2 = (const float*)d_in[3];   // [256,64]
    const float* b2 = (const float*)d_in[4];   // [64]
    const float* ew = (const float*)d_in[5];   // [800000]
    const int* esrc = (const int*)d_in[6];
    const int* edst = (const int*)d_in[7];
    float* out = (float*)d_out;                // [50000,64]

    char* ws = (char*)d_ws;
    size_t off = 0;
    auto take = [&](size_t bytes) -> void* {
        off = (off + 255) & ~(size_t)255;
        void* p = ws + off;
        off += bytes;
        return p;
    };
    u8*  S8   = (u8*)take((size_t)N_NODES * NHID);               // 12.8 MB fp8
    u16* S2   = (u16*)take((size_t)N_NODES * NCLASS * 2);        // 6.4 MB
    u16* W1T  = (u16*)take((size_t)NHID * NFEAT * 2);            // [256][512]
    u16* W2T  = (u16*)take((size_t)NCLASS * NHID * 2);           // [64][256]
    int* deg  = (int*)take((size_t)N_NODES * 4);                 // 0.2 MB
    u32* csr  = (u32*)take((size_t)N_NODES * CSTRIDE * 4);       // 12.8 MB fixed-stride
    int* fill = (int*)take((size_t)NBUCK * 4);
    u64* region = (u64*)take((size_t)NBUCK * BCAP * 8);          // 8.03 MB
    (void)ws_size; (void)in_sizes; (void)n_in; (void)out_size;

    hipMemsetAsync(fill, 0, (size_t)NBUCK * 4, stream);
    prep_scatter_kernel<<<SCB + PW1B + PW2B, 256, 0, stream>>>(
        W1, W1T, W2, W2T, esrc, edst, ew, fill, region);
    gemm1_sort_kernel<<<NBUCK + GB1, 256, 0, stream>>>(
        x, W1T, S8, region, fill, csr, deg);
    spmm1_gemm2_kernel<<<FNB, 256, 0, stream>>>(S8, deg, csr, b1, W2T, S2);
    spmm_bias_lsm_kernel<<<FNB, 256, 0, stream>>>(S2, deg, csr, b2, out);
}

// Round 10
// 259.897 us; speedup vs baseline: 1.1198x; 1.1198x over previous
//
#include <hip/hip_runtime.h>
#include <cstdint>

// GCN forward on MI355X (gfx950). f32 in/out; bf16 MFMA with fp32 accum.
// Round 19: HW fp8 converters replace the software bit-trick.
//  - R18's fp8 halved FETCH (175->82MB) but software decode (~20 VALU/edge)
//    made spmm1 VALU-bound (VALUBusy 27->65%, dur +8us). gfx950 has
//    v_cvt_pk_f32_fp8: 2 packed e4m3fn -> 2 f32 in ONE op. Decode = 2 instrs
//    per 4 feats; encode via v_cvt_pk_fp8_f32 (also fixes denormal flush).
//  - everything else unchanged from R18.
// Chain: memset(fill) -> [bucketA || Wtranspose] -> [gemm1(fp8 out) || csr_sort]
//   -> spmm1+bias+relu+gemm2 -> spmm2+bias+log_softmax.

typedef unsigned char u8;
typedef unsigned short u16;
typedef unsigned int u32;
typedef unsigned long long u64;
typedef __attribute__((ext_vector_type(8))) short bf16x8;
typedef __attribute__((ext_vector_type(4))) float f32x4;
typedef __attribute__((ext_vector_type(2))) float f32x2;

#define N_NODES 50000
#define N_EDGES 800000
#define NFEAT 512
#define NHID 256
#define NCLASS 64
#define CSTRIDE 64        // fixed CSR slots per node (max deg << 64)

#define NBUCK 196         // coarse buckets: dst>>8 (50000/256)
#define BCAP 5120         // bucket region capacity (mean 4096 + 16 sigma)
#define SCB 391           // bucket-scatter blocks: ceil(800000/2048)
#define GB1 782           // gemm1 blocks: ceil(50000/64)
#define PW1B 512          // W1T transpose blocks
#define PW2B 64           // W2T transpose blocks
#define FNB 3125          // fused spmm1+gemm2 blocks: 50000/16

__device__ __forceinline__ float bf2f(u16 h) {
    union { u32 u; float f; } c; c.u = ((u32)h) << 16; return c.f;
}
__device__ __forceinline__ u16 f2bf(float f) {
    union { float f; u32 u; } c; c.f = f;
    u32 u = c.u;
    return (u16)((u + 0x7fffu + ((u >> 16) & 1u)) >> 16);   // RNE
}
__device__ __forceinline__ u32 pk2(float a, float b) {
    return (u32)f2bf(a) | ((u32)f2bf(b) << 16);
}
// f32 -> e4m3fn byte via HW converter (proper denormals, RNE).
__device__ __forceinline__ u8 f2f8(float f) {
    f = fmaxf(fminf(f, 448.f), -448.f);
    return (u8)(__builtin_amdgcn_cvt_pk_fp8_f32(f, f, 0, false) & 0xFF);
}

// async global->LDS, 16B per lane; LDS dest = wave-uniform base + lane*16.
__device__ __forceinline__ void async16(const void* g, void* l) {
    __builtin_amdgcn_global_load_lds(
        (const __attribute__((address_space(1))) void*)(uintptr_t)g,
        (__attribute__((address_space(3))) void*)(uintptr_t)l, 16, 0, 0);
}

// ---------------- dispatch 1: bucketA scatter || W1/W2 transpose+cvt ----------------

__global__ __launch_bounds__(256) void prep_scatter_kernel(
    const float* __restrict__ W1, u16* __restrict__ W1T,
    const float* __restrict__ W2, u16* __restrict__ W2T,
    const int* __restrict__ esrc, const int* __restrict__ edst,
    const float* __restrict__ ew, int* __restrict__ fill, u64* __restrict__ region) {
    __shared__ int cnt[NBUCK];
    __shared__ int base[NBUCK];
    int b = blockIdx.x, tid = threadIdx.x;
    if (b < SCB) {
        if (tid < NBUCK) cnt[tid] = 0;
        __syncthreads();
        int e0 = b * 2048 + tid * 8;
        int d[8], s[8], rk[8];
        float w[8];
        bool act = (e0 < N_EDGES);      // 800000 % 8 == 0: full chunks only
        if (act) {
            int4 d0 = *(const int4*)(edst + e0),  d1 = *(const int4*)(edst + e0 + 4);
            int4 s0 = *(const int4*)(esrc + e0),  s1 = *(const int4*)(esrc + e0 + 4);
            float4 w0 = *(const float4*)(ew + e0), w1 = *(const float4*)(ew + e0 + 4);
            d[0]=d0.x; d[1]=d0.y; d[2]=d0.z; d[3]=d0.w;
            d[4]=d1.x; d[5]=d1.y; d[6]=d1.z; d[7]=d1.w;
            s[0]=s0.x; s[1]=s0.y; s[2]=s0.z; s[3]=s0.w;
            s[4]=s1.x; s[5]=s1.y; s[6]=s1.z; s[7]=s1.w;
            w[0]=w0.x; w[1]=w0.y; w[2]=w0.z; w[3]=w0.w;
            w[4]=w1.x; w[5]=w1.y; w[6]=w1.z; w[7]=w1.w;
            #pragma unroll
            for (int i = 0; i < 8; ++i)
                rk[i] = atomicAdd(&cnt[d[i] >> 8], 1);   // LDS atomic: block-local rank
        }
        __syncthreads();
        if (tid < NBUCK) base[tid] = atomicAdd(&fill[tid], cnt[tid]);
        __syncthreads();
        if (act) {
            #pragma unroll
            for (int i = 0; i < 8; ++i) {
                int g = d[i] >> 8;
                int pos = base[g] + rk[i];
                if (pos < BCAP) {
                    u64 en = ((u64)(d[i] & 255) << 32) |
                             (u64)((u32)s[i] | ((u32)f2bf(w[i]) << 16));
                    region[(size_t)g * BCAP + pos] = en;
                }
            }
        }
    } else if (b < SCB + PW1B) {
        int idx = (b - SCB) * 256 + tid;           // W1T[256][512]
        int n = idx >> 9, k = idx & 511;
        W1T[idx] = f2bf(W1[(size_t)k * NHID + n]);
    } else {
        int idx = (b - SCB - PW1B) * 256 + tid;    // W2T[64][256]
        int n = idx >> 8, k = idx & 255;
        W2T[idx] = f2bf(W2[(size_t)k * NCLASS + n]);
    }
}

// ---------------- gemm1 body: S8[M,256] fp8 = cvt(x[M,512]bf16 @ W1T^T) ----------------
// R15 structure: A reg-staged f32->bf16 (swizzled ds_write), B async16-staged
// (pre-swizzled global source). 4 waves 1x4, BK=64. Epilogue packs fp8 (HW cvt).

__device__ __forceinline__ void gemm1_body(const float* __restrict__ x,
                                           const u16* __restrict__ BT,
                                           u8* __restrict__ C, int M,
                                           int bid, u16* lds) {
    u16* As = lds;             // [64][64] swizzled
    u16* Bs = lds + 64 * 64;   // [256][64] swizzled (B^T: row n, k-contig)

    const int tid  = threadIdx.x;
    const int wv   = tid >> 6, lane = tid & 63;
    const int lm   = lane & 15, quad = lane >> 4;
    const int wcol = wv;                 // WROWS=1, WCOLS=4
    const int m0   = bid * 64;
    const int co0 = ((0 * 4 + quad) ^ (lm & 7)) * 8;
    const int co1 = ((1 * 4 + quad) ^ (lm & 7)) * 8;

    f32x4 acc[4][4];
    #pragma unroll
    for (int r = 0; r < 4; ++r)
        #pragma unroll
        for (int c = 0; c < 4; ++c) acc[r][c] = (f32x4){0.f, 0.f, 0.f, 0.f};

    for (int k0 = 0; k0 < NFEAT; k0 += 64) {
        // issue A f32 loads first (reg), then B DMA, then pack+write.
        int row = tid >> 2, ko = (tid & 3) * 16;
        int gr = m0 + row; if (gr > M - 1) gr = M - 1;
        const float4* gp = (const float4*)(x + (size_t)gr * NFEAT + k0 + ko);
        float4 f0 = gp[0], f1 = gp[1], f2 = gp[2], f3 = gp[3];
        #pragma unroll
        for (int i = 0; i < 8; ++i) {
            int c = i * 256 + tid;
            int n = c >> 3, kb = c & 7;
            async16(BT + (size_t)n * NFEAT + k0 + ((kb ^ (n & 7)) * 8), Bs + c * 8);
        }
        u32 p[8] = {pk2(f0.x, f0.y), pk2(f0.z, f0.w), pk2(f1.x, f1.y), pk2(f1.z, f1.w),
                    pk2(f2.x, f2.y), pk2(f2.z, f2.w), pk2(f3.x, f3.y), pk2(f3.z, f3.w)};
        int ch0 = (2 * (tid & 3))     ^ (row & 7);
        int ch1 = (2 * (tid & 3) + 1) ^ (row & 7);
        *(int4*)(As + row * 64 + ch0 * 8) = *(int4*)&p[0];
        *(int4*)(As + row * 64 + ch1 * 8) = *(int4*)&p[4];
        __syncthreads();   // drains async vmcnt + lgkm (ds_write)

        #pragma unroll
        for (int kk = 0; kk < 2; ++kk) {
            const int co = kk ? co1 : co0;
            bf16x8 af[4], bfv[4];
            #pragma unroll
            for (int rt = 0; rt < 4; ++rt)
                af[rt] = *(const bf16x8*)(As + (rt * 16 + lm) * 64 + co);
            #pragma unroll
            for (int ct = 0; ct < 4; ++ct) {
                int n = wcol * 64 + ct * 16 + lm;
                bfv[ct] = *(const bf16x8*)(Bs + n * 64 + co);
            }
            #pragma unroll
            for (int rt = 0; rt < 4; ++rt)
                #pragma unroll
                for (int ct = 0; ct < 4; ++ct)
                    acc[rt][ct] = __builtin_amdgcn_mfma_f32_16x16x32_bf16(
                        af[rt], bfv[ct], acc[rt][ct], 0, 0, 0);
        }
        __syncthreads();
    }

    // epilogue: fp8 pack through LDS (u8 [64][256] = 16KB), linear store
    u8* lds8 = (u8*)lds;
    #pragma unroll
    for (int rt = 0; rt < 4; ++rt)
        #pragma unroll
        for (int ct = 0; ct < 4; ++ct) {
            int col = wcol * 64 + ct * 16 + lm;
            #pragma unroll
            for (int r = 0; r < 4; ++r) {
                int row = rt * 16 + quad * 4 + r;   // C/D: row = quad*4 + reg
                lds8[row * 256 + col] = f2f8(acc[rt][ct][r]);
            }
        }
    __syncthreads();
    #pragma unroll
    for (int i = 0; i < 4; ++i) {
        int c = i * 256 + tid;                      // 1024 chunks of 16B
        int row = c >> 4, ch = c & 15;
        if (m0 + row < M)
            *(int4*)(C + (size_t)(m0 + row) * 256 + ch * 16) = *(const int4*)(lds8 + c * 16);
    }
}

// ---------------- dispatch 2: gemm1 || csr_sort ----------------

__global__ __launch_bounds__(256) void gemm1_sort_kernel(
    const float* __restrict__ x, const u16* __restrict__ W1T, u8* __restrict__ S8,
    const u64* __restrict__ region, const int* __restrict__ fill,
    u32* __restrict__ csr, int* __restrict__ deg) {
    __shared__ __align__(16) u16 lds[(64 + 256) * 64];   // 40KB
    int b = blockIdx.x, tid = threadIdx.x;
    if (b < NBUCK) {
        int* cnt2 = (int*)lds;          // [256]
        cnt2[tid] = 0;
        __syncthreads();
        int Eb = fill[b]; if (Eb > BCAP) Eb = BCAP;
        for (int i = tid; i < Eb; i += 256) {
            u64 en = region[(size_t)b * BCAP + i];
            int dlo = (int)(en >> 32) & 255;
            int r = atomicAdd(&cnt2[dlo], 1);
            if (r < CSTRIDE)
                csr[(size_t)(b * 256 + dlo) * CSTRIDE + r] = (u32)en;
        }
        __syncthreads();
        int node = b * 256 + tid;
        if (node < N_NODES) {
            int dg = cnt2[tid]; if (dg > CSTRIDE) dg = CSTRIDE;
            deg[node] = dg;
        }
    } else {
        gemm1_body(x, W1T, S8, N_NODES, b - NBUCK, lds);
    }
}

// ---------------- fused SpMM1(fp8 gather, HW cvt) + bias + ReLU + gemm2 ----------------
// Block = 4 waves = 16 nodes. Phase 1: 4-node interleaved, 8-deep batches
// (32 gathers in flight/wave); HW v_cvt_pk_f32_fp8 decode (2 ops / 4 feats);
// tails zero-selected. Phase 2: 16x64x256 MFMA vs W2T direct from L2.

__global__ __launch_bounds__(256) void spmm1_gemm2_kernel(
    const u8* __restrict__ S8, const int* __restrict__ deg,
    const u32* __restrict__ csr, const float* __restrict__ bias1,
    const u16* __restrict__ W2T, u16* __restrict__ S2) {
    __shared__ __align__(16) u16 Hs[16 * 256];   // [16][256] swizzled; reused for repack

    const int tid  = threadIdx.x;
    const int wv   = tid >> 6, lane = tid & 63;
    const int lm   = lane & 15, quad = lane >> 4;
    const int b    = blockIdx.x;

    float4 bv = *(const float4*)(bias1 + lane * 4);

    int begs[4], degs[4];
    int maxd = 0;
    #pragma unroll
    for (int n = 0; n < 4; ++n) {
        int node = __builtin_amdgcn_readfirstlane(b * 16 + wv * 4 + n);
        begs[n] = node * CSTRIDE;
        degs[n] = deg[node];
        maxd = max(maxd, degs[n]);
    }

    float a[4][4];
    #pragma unroll
    for (int n = 0; n < 4; ++n)
        #pragma unroll
        for (int k = 0; k < 4; ++k) a[n][k] = 0.f;

    for (int kb = 0; kb < maxd; kb += 8) {
        u32 e[4][8];
        #pragma unroll
        for (int n = 0; n < 4; ++n)
            #pragma unroll
            for (int i = 0; i < 8; ++i) {
                u32 t = csr[begs[n] + kb + i];            // uniform -> s_load
                e[n][i] = (kb + i < degs[n]) ? t : 0u;    // pad: src 0, w 0
            }
        u32 q[4][8];
        #pragma unroll
        for (int n = 0; n < 4; ++n)
            #pragma unroll
            for (int i = 0; i < 8; ++i)
                q[n][i] = *(const u32*)(S8 + (size_t)(e[n][i] & 0xFFFFu) * NHID + lane * 4);
        #pragma unroll
        for (int n = 0; n < 4; ++n)
            #pragma unroll
            for (int i = 0; i < 8; ++i) {
                float w = bf2f((u16)(e[n][i] >> 16));
                f32x2 lo = __builtin_amdgcn_cvt_pk_f32_fp8((int)q[n][i], false);
                f32x2 hi = __builtin_amdgcn_cvt_pk_f32_fp8((int)q[n][i], true);
                a[n][0] += w * lo.x; a[n][1] += w * lo.y;
                a[n][2] += w * hi.x; a[n][3] += w * hi.y;
            }
    }

    #pragma unroll
    for (int n = 0; n < 4; ++n) {
        int lrow = wv * 4 + n;
        float a0 = fmaxf(a[n][0] + bv.x, 0.f);
        float a1 = fmaxf(a[n][1] + bv.y, 0.f);
        float a2 = fmaxf(a[n][2] + bv.z, 0.f);
        float a3 = fmaxf(a[n][3] + bv.w, 0.f);
        int ch = (lane >> 1) ^ (lrow & 7);
        u32* dp = (u32*)(Hs + lrow * 256 + ch * 8 + (lane & 1) * 4);
        dp[0] = pk2(a0, a1);
        dp[1] = pk2(a2, a3);
    }
    __syncthreads();

    // ---- phase 2: S2[16][64] = H[16][256] @ W2T^T, B direct from L2 ----
    f32x4 acc = (f32x4){0.f, 0.f, 0.f, 0.f};
    #pragma unroll
    for (int k0 = 0; k0 < NHID; k0 += 64) {
        #pragma unroll
        for (int kk = 0; kk < 2; ++kk) {
            int ca = ((k0 >> 3) + kk * 4 + quad) ^ (lm & 7);
            bf16x8 af = *(const bf16x8*)(Hs + lm * 256 + ca * 8);
            int n = wv * 16 + lm;
            bf16x8 bf = *(const bf16x8*)(W2T + (size_t)n * NHID + k0 + kk * 32 + quad * 8);
            acc = __builtin_amdgcn_mfma_f32_16x16x32_bf16(af, bf, acc, 0, 0, 0);
        }
    }
    __syncthreads();

    #pragma unroll
    for (int r = 0; r < 4; ++r) {
        int row = quad * 4 + r;                  // C/D: row = quad*4 + reg
        Hs[row * 64 + wv * 16 + lm] = f2bf(acc[r]);
    }
    __syncthreads();
    *(ushort4*)(S2 + (size_t)b * 1024 + tid * 4) = *(const ushort4*)(Hs + tid * 4);
}

// ---------------- SpMM2 + bias + log_softmax (4 nodes/wave interleaved) ----------------

__global__ __launch_bounds__(256) void spmm_bias_lsm_kernel(
    const u16* __restrict__ S, const int* __restrict__ deg,
    const u32* __restrict__ csr, const float* __restrict__ bias,
    float* __restrict__ out) {
    const int tid = threadIdx.x;
    const int wv = tid >> 6, lane = tid & 63;
    const int b = blockIdx.x;

    int begs[4], degs[4];
    int maxd = 0;
    #pragma unroll
    for (int n = 0; n < 4; ++n) {
        int node = __builtin_amdgcn_readfirstlane(b * 16 + wv * 4 + n);
        begs[n] = node * CSTRIDE;
        degs[n] = deg[node];
        maxd = max(maxd, degs[n]);
    }

    float acc[4] = {0.f, 0.f, 0.f, 0.f};
    for (int kb = 0; kb < maxd; kb += 8) {
        u32 e[4][8];
        #pragma unroll
        for (int n = 0; n < 4; ++n)
            #pragma unroll
            for (int i = 0; i < 8; ++i) {
                u32 t = csr[begs[n] + kb + i];            // uniform -> s_load
                e[n][i] = (kb + i < degs[n]) ? t : 0u;    // pad: src 0, w 0
            }
        u16 v[4][8];
        #pragma unroll
        for (int n = 0; n < 4; ++n)
            #pragma unroll
            for (int i = 0; i < 8; ++i)
                v[n][i] = S[(size_t)(e[n][i] & 0xFFFFu) * NCLASS + lane];
        #pragma unroll
        for (int n = 0; n < 4; ++n)
            #pragma unroll
            for (int i = 0; i < 8; ++i)
                acc[n] += bf2f((u16)(e[n][i] >> 16)) * bf2f(v[n][i]);
    }

    float bl = bias[lane];
    #pragma unroll
    for (int n = 0; n < 4; ++n) {
        int node = b * 16 + wv * 4 + n;
        float x = acc[n] + bl;
        float m = x;
        #pragma unroll
        for (int off = 32; off > 0; off >>= 1) m = fmaxf(m, __shfl_xor(m, off));
        float e = expf(x - m);
        float ssum = e;
        #pragma unroll
        for (int off = 32; off > 0; off >>= 1) ssum += __shfl_xor(ssum, off);
        out[(size_t)node * NCLASS + lane] = x - m - logf(ssum);
    }
}

// ---------------- launch ----------------

extern "C" void kernel_launch(void* const* d_in, const int* in_sizes, int n_in,
                              void* d_out, int out_size, void* d_ws, size_t ws_size,
                              hipStream_t stream) {
    const float* x  = (const float*)d_in[0];   // [50000,512]
    const float* W1 = (const float*)d_in[1];   // [512,256]
    const float* b1 = (const float*)d_in[2];   // [256]
    const float* W2 = (const float*)d_in[3];   // [256,64]
    const float* b2 = (const float*)d_in[4];   // [64]
    const float* ew = (const float*)d_in[5];   // [800000]
    const int* esrc = (const int*)d_in[6];
    const int* edst = (const int*)d_in[7];
    float* out = (float*)d_out;                // [50000,64]

    char* ws = (char*)d_ws;
    size_t off = 0;
    auto take = [&](size_t bytes) -> void* {
        off = (off + 255) & ~(size_t)255;
        void* p = ws + off;
        off += bytes;
        return p;
    };
    u8*  S8   = (u8*)take((size_t)N_NODES * NHID);               // 12.8 MB fp8
    u16* S2   = (u16*)take((size_t)N_NODES * NCLASS * 2);        // 6.4 MB
    u16* W1T  = (u16*)take((size_t)NHID * NFEAT * 2);            // [256][512]
    u16* W2T  = (u16*)take((size_t)NCLASS * NHID * 2);           // [64][256]
    int* deg  = (int*)take((size_t)N_NODES * 4);                 // 0.2 MB
    u32* csr  = (u32*)take((size_t)N_NODES * CSTRIDE * 4);       // 12.8 MB fixed-stride
    int* fill = (int*)take((size_t)NBUCK * 4);
    u64* region = (u64*)take((size_t)NBUCK * BCAP * 8);          // 8.03 MB
    (void)ws_size; (void)in_sizes; (void)n_in; (void)out_size;

    hipMemsetAsync(fill, 0, (size_t)NBUCK * 4, stream);
    prep_scatter_kernel<<<SCB + PW1B + PW2B, 256, 0, stream>>>(
        W1, W1T, W2, W2T, esrc, edst, ew, fill, region);
    gemm1_sort_kernel<<<NBUCK + GB1, 256, 0, stream>>>(
        x, W1T, S8, region, fill, csr, deg);
    spmm1_gemm2_kernel<<<FNB, 256, 0, stream>>>(S8, deg, csr, b1, W2T, S2);
    spmm_bias_lsm_kernel<<<FNB, 256, 0, stream>>>(S2, deg, csr, b2, out);
}

// Round 11
// 256.086 us; speedup vs baseline: 1.1365x; 1.0149x over previous
//
#include <hip/hip_runtime.h>
#include <cstdint>

// GCN forward on MI355X (gfx950). f32 in/out; bf16 MFMA with fp32 accum.
// Round 20: gemm1 K-loop re-pipelined with raw barriers + counted waits.
//  - __syncthreads drains vmcnt(0) every K-step -> A HBM latency (~900cy) and
//    B L2 latency fully exposed per iteration (74% idle). New structure:
//    A double-buffered (reg-prefetch issued pre-b1, consumed next iter), B
//    single-buffered with DMA issued post-b2; raw s_barrier + asm vmcnt/lgkm
//    (T3/T4 minimum template), sched_barrier(0) pinning per rule #18.
//  - happens-before: As[t&1] rewritten at t+2 after writer passes b2(t+1);
//    Bs DMA'd only post-b2 (reads retired) and drained pre-b1 of t+1.
//  - everything else unchanged from R19.
// Chain: memset(fill) -> [bucketA || Wtranspose] -> [gemm1(fp8 out) || csr_sort]
//   -> spmm1+bias+relu+gemm2 -> spmm2+bias+log_softmax.

typedef unsigned char u8;
typedef unsigned short u16;
typedef unsigned int u32;
typedef unsigned long long u64;
typedef __attribute__((ext_vector_type(8))) short bf16x8;
typedef __attribute__((ext_vector_type(4))) float f32x4;
typedef __attribute__((ext_vector_type(2))) float f32x2;

#define N_NODES 50000
#define N_EDGES 800000
#define NFEAT 512
#define NHID 256
#define NCLASS 64
#define CSTRIDE 64        // fixed CSR slots per node (max deg << 64)

#define NBUCK 196         // coarse buckets: dst>>8 (50000/256)
#define BCAP 5120         // bucket region capacity (mean 4096 + 16 sigma)
#define SCB 391           // bucket-scatter blocks: ceil(800000/2048)
#define GB1 782           // gemm1 blocks: ceil(50000/64)
#define PW1B 512          // W1T transpose blocks
#define PW2B 64           // W2T transpose blocks
#define FNB 3125          // fused spmm1+gemm2 blocks: 50000/16

__device__ __forceinline__ float bf2f(u16 h) {
    union { u32 u; float f; } c; c.u = ((u32)h) << 16; return c.f;
}
__device__ __forceinline__ u16 f2bf(float f) {
    union { float f; u32 u; } c; c.f = f;
    u32 u = c.u;
    return (u16)((u + 0x7fffu + ((u >> 16) & 1u)) >> 16);   // RNE
}
__device__ __forceinline__ u32 pk2(float a, float b) {
    return (u32)f2bf(a) | ((u32)f2bf(b) << 16);
}
// f32 -> e4m3fn byte via HW converter (proper denormals, RNE).
__device__ __forceinline__ u8 f2f8(float f) {
    f = fmaxf(fminf(f, 448.f), -448.f);
    return (u8)(__builtin_amdgcn_cvt_pk_fp8_f32(f, f, 0, false) & 0xFF);
}

// async global->LDS, 16B per lane; LDS dest = wave-uniform base + lane*16.
__device__ __forceinline__ void async16(const void* g, void* l) {
    __builtin_amdgcn_global_load_lds(
        (const __attribute__((address_space(1))) void*)(uintptr_t)g,
        (__attribute__((address_space(3))) void*)(uintptr_t)l, 16, 0, 0);
}

// ---------------- dispatch 1: bucketA scatter || W1/W2 transpose+cvt ----------------

__global__ __launch_bounds__(256) void prep_scatter_kernel(
    const float* __restrict__ W1, u16* __restrict__ W1T,
    const float* __restrict__ W2, u16* __restrict__ W2T,
    const int* __restrict__ esrc, const int* __restrict__ edst,
    const float* __restrict__ ew, int* __restrict__ fill, u64* __restrict__ region) {
    __shared__ int cnt[NBUCK];
    __shared__ int base[NBUCK];
    int b = blockIdx.x, tid = threadIdx.x;
    if (b < SCB) {
        if (tid < NBUCK) cnt[tid] = 0;
        __syncthreads();
        int e0 = b * 2048 + tid * 8;
        int d[8], s[8], rk[8];
        float w[8];
        bool act = (e0 < N_EDGES);      // 800000 % 8 == 0: full chunks only
        if (act) {
            int4 d0 = *(const int4*)(edst + e0),  d1 = *(const int4*)(edst + e0 + 4);
            int4 s0 = *(const int4*)(esrc + e0),  s1 = *(const int4*)(esrc + e0 + 4);
            float4 w0 = *(const float4*)(ew + e0), w1 = *(const float4*)(ew + e0 + 4);
            d[0]=d0.x; d[1]=d0.y; d[2]=d0.z; d[3]=d0.w;
            d[4]=d1.x; d[5]=d1.y; d[6]=d1.z; d[7]=d1.w;
            s[0]=s0.x; s[1]=s0.y; s[2]=s0.z; s[3]=s0.w;
            s[4]=s1.x; s[5]=s1.y; s[6]=s1.z; s[7]=s1.w;
            w[0]=w0.x; w[1]=w0.y; w[2]=w0.z; w[3]=w0.w;
            w[4]=w1.x; w[5]=w1.y; w[6]=w1.z; w[7]=w1.w;
            #pragma unroll
            for (int i = 0; i < 8; ++i)
                rk[i] = atomicAdd(&cnt[d[i] >> 8], 1);   // LDS atomic: block-local rank
        }
        __syncthreads();
        if (tid < NBUCK) base[tid] = atomicAdd(&fill[tid], cnt[tid]);
        __syncthreads();
        if (act) {
            #pragma unroll
            for (int i = 0; i < 8; ++i) {
                int g = d[i] >> 8;
                int pos = base[g] + rk[i];
                if (pos < BCAP) {
                    u64 en = ((u64)(d[i] & 255) << 32) |
                             (u64)((u32)s[i] | ((u32)f2bf(w[i]) << 16));
                    region[(size_t)g * BCAP + pos] = en;
                }
            }
        }
    } else if (b < SCB + PW1B) {
        int idx = (b - SCB) * 256 + tid;           // W1T[256][512]
        int n = idx >> 9, k = idx & 511;
        W1T[idx] = f2bf(W1[(size_t)k * NHID + n]);
    } else {
        int idx = (b - SCB - PW1B) * 256 + tid;    // W2T[64][256]
        int n = idx >> 8, k = idx & 255;
        W2T[idx] = f2bf(W2[(size_t)k * NCLASS + n]);
    }
}

// ---------------- gemm1 body: S8[M,256] fp8 = cvt(x[M,512]bf16 @ W1T^T) ----------------
// Pipelined: A dbuf (2x[64][64]), B single ([256][64]); raw barriers; A-loads
// issued pre-b1 (consumed next iter), B-DMA issued post-b2 (drained pre-b1).

__device__ __forceinline__ void gemm1_body(const float* __restrict__ x,
                                           const u16* __restrict__ BT,
                                           u8* __restrict__ C, int M,
                                           int bid, u16* lds) {
    u16* As0 = lds;                  // 2 x 4096 u16 (A dbuf)
    u16* Bs  = lds + 2 * 4096;       // 16384 u16 (B single)

    const int tid  = threadIdx.x;
    const int wv   = tid >> 6, lane = tid & 63;
    const int lm   = lane & 15, quad = lane >> 4;
    const int wcol = wv;                 // WROWS=1, WCOLS=4
    const int m0   = bid * 64;
    const int co0 = ((0 * 4 + quad) ^ (lm & 7)) * 8;
    const int co1 = ((1 * 4 + quad) ^ (lm & 7)) * 8;
    const int arow = tid >> 2;
    int gr = m0 + arow; if (gr > M - 1) gr = M - 1;
    const float* gpb = x + (size_t)gr * NFEAT + (tid & 3) * 16;
    const int ch0 = (2 * (tid & 3)) ^ (arow & 7);
    const int ch1 = (2 * (tid & 3) + 1) ^ (arow & 7);

    f32x4 acc[4][4];
    #pragma unroll
    for (int r = 0; r < 4; ++r)
        #pragma unroll
        for (int c = 0; c < 4; ++c) acc[r][c] = (f32x4){0.f, 0.f, 0.f, 0.f};

    // prologue: issue A(0) (older), then B(0) DMA (younger)
    float4 f0, f1, f2, f3;
    {
        const float4* gp = (const float4*)gpb;
        f0 = gp[0]; f1 = gp[1]; f2 = gp[2]; f3 = gp[3];
    }
    #pragma unroll
    for (int i = 0; i < 8; ++i) {
        int c = i * 256 + tid;
        int n = c >> 3, kb = c & 7;
        async16(BT + (size_t)n * NFEAT + ((kb ^ (n & 7)) * 8), Bs + c * 8);
    }

    for (int t = 0; t < 8; ++t) {
        u16* As = As0 + (t & 1) * 4096;
        // pack A(t): compiler inserts counted vmcnt wait for f0..f3 (B stays in flight)
        u32 p[8] = {pk2(f0.x, f0.y), pk2(f0.z, f0.w), pk2(f1.x, f1.y), pk2(f1.z, f1.w),
                    pk2(f2.x, f2.y), pk2(f2.z, f2.w), pk2(f3.x, f3.y), pk2(f3.z, f3.w)};
        *(int4*)(As + arow * 64 + ch0 * 8) = *(int4*)&p[0];
        *(int4*)(As + arow * 64 + ch1 * 8) = *(int4*)&p[4];
        // drain own B(t) DMA + ds_write before signaling barrier
        asm volatile("s_waitcnt vmcnt(0) lgkmcnt(0)" ::: "memory");
        __builtin_amdgcn_sched_barrier(0);
        if (t < 7) {                 // issue A(t+1): survives raw barrier, lands under MFMA
            const float4* gp = (const float4*)(gpb + (t + 1) * 64);
            f0 = gp[0]; f1 = gp[1]; f2 = gp[2]; f3 = gp[3];
        }
        __builtin_amdgcn_s_barrier();            // b1: As(t)+Bs(t) visible to all
        __builtin_amdgcn_sched_barrier(0);

        #pragma unroll
        for (int kk = 0; kk < 2; ++kk) {
            const int co = kk ? co1 : co0;
            bf16x8 af[4], bfv[4];
            #pragma unroll
            for (int rt = 0; rt < 4; ++rt)
                af[rt] = *(const bf16x8*)(As + (rt * 16 + lm) * 64 + co);
            #pragma unroll
            for (int ct = 0; ct < 4; ++ct) {
                int n = wcol * 64 + ct * 16 + lm;
                bfv[ct] = *(const bf16x8*)(Bs + n * 64 + co);
            }
            #pragma unroll
            for (int rt = 0; rt < 4; ++rt)
                #pragma unroll
                for (int ct = 0; ct < 4; ++ct)
                    acc[rt][ct] = __builtin_amdgcn_mfma_f32_16x16x32_bf16(
                        af[rt], bfv[ct], acc[rt][ct], 0, 0, 0);
        }
        __builtin_amdgcn_s_barrier();            // b2 (bare): all Bs reads retired
        __builtin_amdgcn_sched_barrier(0);
        if (t < 7) {                 // issue B(t+1) post-b2: safe, drained pre-b1 of t+1
            int k0 = (t + 1) * 64;
            #pragma unroll
            for (int i = 0; i < 8; ++i) {
                int c = i * 256 + tid;
                int n = c >> 3, kb = c & 7;
                async16(BT + (size_t)n * NFEAT + k0 + ((kb ^ (n & 7)) * 8), Bs + c * 8);
            }
        }
    }

    // epilogue: fp8 pack through LDS (u8 [64][256] = 16KB), linear store
    u8* lds8 = (u8*)lds;
    #pragma unroll
    for (int rt = 0; rt < 4; ++rt)
        #pragma unroll
        for (int ct = 0; ct < 4; ++ct) {
            int col = wcol * 64 + ct * 16 + lm;
            #pragma unroll
            for (int r = 0; r < 4; ++r) {
                int row = rt * 16 + quad * 4 + r;   // C/D: row = quad*4 + reg
                lds8[row * 256 + col] = f2f8(acc[rt][ct][r]);
            }
        }
    __syncthreads();
    #pragma unroll
    for (int i = 0; i < 4; ++i) {
        int c = i * 256 + tid;                      // 1024 chunks of 16B
        int row = c >> 4, ch = c & 15;
        if (m0 + row < M)
            *(int4*)(C + (size_t)(m0 + row) * 256 + ch * 16) = *(const int4*)(lds8 + c * 16);
    }
}

// ---------------- dispatch 2: gemm1 || csr_sort ----------------

__global__ __launch_bounds__(256) void gemm1_sort_kernel(
    const float* __restrict__ x, const u16* __restrict__ W1T, u8* __restrict__ S8,
    const u64* __restrict__ region, const int* __restrict__ fill,
    u32* __restrict__ csr, int* __restrict__ deg) {
    __shared__ __align__(16) u16 lds[24576];   // 48KB: A dbuf + B + epilogue scratch
    int b = blockIdx.x, tid = threadIdx.x;
    if (b < NBUCK) {
        int* cnt2 = (int*)lds;          // [256]
        cnt2[tid] = 0;
        __syncthreads();
        int Eb = fill[b]; if (Eb > BCAP) Eb = BCAP;
        for (int i = tid; i < Eb; i += 256) {
            u64 en = region[(size_t)b * BCAP + i];
            int dlo = (int)(en >> 32) & 255;
            int r = atomicAdd(&cnt2[dlo], 1);
            if (r < CSTRIDE)
                csr[(size_t)(b * 256 + dlo) * CSTRIDE + r] = (u32)en;
        }
        __syncthreads();
        int node = b * 256 + tid;
        if (node < N_NODES) {
            int dg = cnt2[tid]; if (dg > CSTRIDE) dg = CSTRIDE;
            deg[node] = dg;
        }
    } else {
        gemm1_body(x, W1T, S8, N_NODES, b - NBUCK, lds);
    }
}

// ---------------- fused SpMM1(fp8 gather, HW cvt) + bias + ReLU + gemm2 ----------------

__global__ __launch_bounds__(256) void spmm1_gemm2_kernel(
    const u8* __restrict__ S8, const int* __restrict__ deg,
    const u32* __restrict__ csr, const float* __restrict__ bias1,
    const u16* __restrict__ W2T, u16* __restrict__ S2) {
    __shared__ __align__(16) u16 Hs[16 * 256];   // [16][256] swizzled; reused for repack

    const int tid  = threadIdx.x;
    const int wv   = tid >> 6, lane = tid & 63;
    const int lm   = lane & 15, quad = lane >> 4;
    const int b    = blockIdx.x;

    float4 bv = *(const float4*)(bias1 + lane * 4);

    int begs[4], degs[4];
    int maxd = 0;
    #pragma unroll
    for (int n = 0; n < 4; ++n) {
        int node = __builtin_amdgcn_readfirstlane(b * 16 + wv * 4 + n);
        begs[n] = node * CSTRIDE;
        degs[n] = deg[node];
        maxd = max(maxd, degs[n]);
    }

    float a[4][4];
    #pragma unroll
    for (int n = 0; n < 4; ++n)
        #pragma unroll
        for (int k = 0; k < 4; ++k) a[n][k] = 0.f;

    for (int kb = 0; kb < maxd; kb += 8) {
        u32 e[4][8];
        #pragma unroll
        for (int n = 0; n < 4; ++n)
            #pragma unroll
            for (int i = 0; i < 8; ++i) {
                u32 t = csr[begs[n] + kb + i];            // uniform -> s_load
                e[n][i] = (kb + i < degs[n]) ? t : 0u;    // pad: src 0, w 0
            }
        u32 q[4][8];
        #pragma unroll
        for (int n = 0; n < 4; ++n)
            #pragma unroll
            for (int i = 0; i < 8; ++i)
                q[n][i] = *(const u32*)(S8 + (size_t)(e[n][i] & 0xFFFFu) * NHID + lane * 4);
        #pragma unroll
        for (int n = 0; n < 4; ++n)
            #pragma unroll
            for (int i = 0; i < 8; ++i) {
                float w = bf2f((u16)(e[n][i] >> 16));
                f32x2 lo = __builtin_amdgcn_cvt_pk_f32_fp8((int)q[n][i], false);
                f32x2 hi = __builtin_amdgcn_cvt_pk_f32_fp8((int)q[n][i], true);
                a[n][0] += w * lo.x; a[n][1] += w * lo.y;
                a[n][2] += w * hi.x; a[n][3] += w * hi.y;
            }
    }

    #pragma unroll
    for (int n = 0; n < 4; ++n) {
        int lrow = wv * 4 + n;
        float a0 = fmaxf(a[n][0] + bv.x, 0.f);
        float a1 = fmaxf(a[n][1] + bv.y, 0.f);
        float a2 = fmaxf(a[n][2] + bv.z, 0.f);
        float a3 = fmaxf(a[n][3] + bv.w, 0.f);
        int ch = (lane >> 1) ^ (lrow & 7);
        u32* dp = (u32*)(Hs + lrow * 256 + ch * 8 + (lane & 1) * 4);
        dp[0] = pk2(a0, a1);
        dp[1] = pk2(a2, a3);
    }
    __syncthreads();

    // ---- phase 2: S2[16][64] = H[16][256] @ W2T^T, B direct from L2 ----
    f32x4 acc = (f32x4){0.f, 0.f, 0.f, 0.f};
    #pragma unroll
    for (int k0 = 0; k0 < NHID; k0 += 64) {
        #pragma unroll
        for (int kk = 0; kk < 2; ++kk) {
            int ca = ((k0 >> 3) + kk * 4 + quad) ^ (lm & 7);
            bf16x8 af = *(const bf16x8*)(Hs + lm * 256 + ca * 8);
            int n = wv * 16 + lm;
            bf16x8 bf = *(const bf16x8*)(W2T + (size_t)n * NHID + k0 + kk * 32 + quad * 8);
            acc = __builtin_amdgcn_mfma_f32_16x16x32_bf16(af, bf, acc, 0, 0, 0);
        }
    }
    __syncthreads();

    #pragma unroll
    for (int r = 0; r < 4; ++r) {
        int row = quad * 4 + r;                  // C/D: row = quad*4 + reg
        Hs[row * 64 + wv * 16 + lm] = f2bf(acc[r]);
    }
    __syncthreads();
    *(ushort4*)(S2 + (size_t)b * 1024 + tid * 4) = *(const ushort4*)(Hs + tid * 4);
}

// ---------------- SpMM2 + bias + log_softmax (4 nodes/wave interleaved) ----------------

__global__ __launch_bounds__(256) void spmm_bias_lsm_kernel(
    const u16* __restrict__ S, const int* __restrict__ deg,
    const u32* __restrict__ csr, const float* __restrict__ bias,
    float* __restrict__ out) {
    const int tid = threadIdx.x;
    const int wv = tid >> 6, lane = tid & 63;
    const int b = blockIdx.x;

    int begs[4], degs[4];
    int maxd = 0;
    #pragma unroll
    for (int n = 0; n < 4; ++n) {
        int node = __builtin_amdgcn_readfirstlane(b * 16 + wv * 4 + n);
        begs[n] = node * CSTRIDE;
        degs[n] = deg[node];
        maxd = max(maxd, degs[n]);
    }

    float acc[4] = {0.f, 0.f, 0.f, 0.f};
    for (int kb = 0; kb < maxd; kb += 8) {
        u32 e[4][8];
        #pragma unroll
        for (int n = 0; n < 4; ++n)
            #pragma unroll
            for (int i = 0; i < 8; ++i) {
                u32 t = csr[begs[n] + kb + i];            // uniform -> s_load
                e[n][i] = (kb + i < degs[n]) ? t : 0u;    // pad: src 0, w 0
            }
        u16 v[4][8];
        #pragma unroll
        for (int n = 0; n < 4; ++n)
            #pragma unroll
            for (int i = 0; i < 8; ++i)
                v[n][i] = S[(size_t)(e[n][i] & 0xFFFFu) * NCLASS + lane];
        #pragma unroll
        for (int n = 0; n < 4; ++n)
            #pragma unroll
            for (int i = 0; i < 8; ++i)
                acc[n] += bf2f((u16)(e[n][i] >> 16)) * bf2f(v[n][i]);
    }

    float bl = bias[lane];
    #pragma unroll
    for (int n = 0; n < 4; ++n) {
        int node = b * 16 + wv * 4 + n;
        float x = acc[n] + bl;
        float m = x;
        #pragma unroll
        for (int off = 32; off > 0; off >>= 1) m = fmaxf(m, __shfl_xor(m, off));
        float e = expf(x - m);
        float ssum = e;
        #pragma unroll
        for (int off = 32; off > 0; off >>= 1) ssum += __shfl_xor(ssum, off);
        out[(size_t)node * NCLASS + lane] = x - m - logf(ssum);
    }
}

// ---------------- launch ----------------

extern "C" void kernel_launch(void* const* d_in, const int* in_sizes, int n_in,
                              void* d_out, int out_size, void* d_ws, size_t ws_size,
                              hipStream_t stream) {
    const float* x  = (const float*)d_in[0];   // [50000,512]
    const float* W1 = (const float*)d_in[1];   // [512,256]
    const float* b1 = (const float*)d_in[2];   // [256]
    const float* W2 = (const float*)d_in[3];   // [256,64]
    const float* b2 = (const float*)d_in[4];   // [64]
    const float* ew = (const float*)d_in[5];   // [800000]
    const int* esrc = (const int*)d_in[6];
    const int* edst = (const int*)d_in[7];
    float* out = (float*)d_out;                // [50000,64]

    char* ws = (char*)d_ws;
    size_t off = 0;
    auto take = [&](size_t bytes) -> void* {
        off = (off + 255) & ~(size_t)255;
        void* p = ws + off;
        off += bytes;
        return p;
    };
    u8*  S8   = (u8*)take((size_t)N_NODES * NHID);               // 12.8 MB fp8
    u16* S2   = (u16*)take((size_t)N_NODES * NCLASS * 2);        // 6.4 MB
    u16* W1T  = (u16*)take((size_t)NHID * NFEAT * 2);            // [256][512]
    u16* W2T  = (u16*)take((size_t)NCLASS * NHID * 2);           // [64][256]
    int* deg  = (int*)take((size_t)N_NODES * 4);                 // 0.2 MB
    u32* csr  = (u32*)take((size_t)N_NODES * CSTRIDE * 4);       // 12.8 MB fixed-stride
    int* fill = (int*)take((size_t)NBUCK * 4);
    u64* region = (u64*)take((size_t)NBUCK * BCAP * 8);          // 8.03 MB
    (void)ws_size; (void)in_sizes; (void)n_in; (void)out_size;

    hipMemsetAsync(fill, 0, (size_t)NBUCK * 4, stream);
    prep_scatter_kernel<<<SCB + PW1B + PW2B, 256, 0, stream>>>(
        W1, W1T, W2, W2T, esrc, edst, ew, fill, region);
    gemm1_sort_kernel<<<NBUCK + GB1, 256, 0, stream>>>(
        x, W1T, S8, region, fill, csr, deg);
    spmm1_gemm2_kernel<<<FNB, 256, 0, stream>>>(S8, deg, csr, b1, W2T, S2);
    spmm_bias_lsm_kernel<<<FNB, 256, 0, stream>>>(S2, deg, csr, b2, out);
}